// Round 2
// baseline (685.699 us; speedup 1.0000x reference)
//
#include <hip/hip_runtime.h>
#include <hip/hip_bf16.h>

// ---------------------------------------------------------------------------
// EdgeNetwork: out[e] = tanh(relu(cat(h[dst[e]], h[src[e]], dR[e]) @ W1 + b1) @ W2 + b2)
// E=640000, F=128, MID=192, OUT=128.  bf16 MFMA (16x16x32), fp32 accumulate.
// R2: pre-converted bf16 h + direct-global a-frag gather (no LDS A tile, one
//     barrier), frag-major weights w/ imm-offset loads, cheap tanh, nt stores.
// ---------------------------------------------------------------------------

#define F_IN   128
#define MID    192
#define OUT_N  128
#define M_TILE 64
#define H_STRIDE 200        // bf16 elems; 400 B row -> 100 dwords == 4 mod 32 banks

typedef __attribute__((ext_vector_type(8))) short bf16x8;   // 8 bf16 = 4 VGPRs
typedef __attribute__((ext_vector_type(4))) float f32x4;

__device__ __forceinline__ unsigned short f2bf(float f) {
    unsigned u = __builtin_bit_cast(unsigned, f);
    return (unsigned short)((u + 0x8000u) >> 16);   // round-half-up: <=0.5 ulp
}

// h (fp32, node-major) -> hb (bf16, node-major)
__global__ void pack_h(const float* __restrict__ h, unsigned short* __restrict__ hb, int n4) {
    int i = blockIdx.x * 256 + threadIdx.x;
    if (i >= n4) return;
    float4 v = ((const float4*)h)[i];
    ushort4 b;
    b.x = f2bf(v.x); b.y = f2bf(v.y); b.z = f2bf(v.z); b.w = f2bf(v.w);
    ((ushort4*)hb)[i] = b;
}

// Weights -> bf16, frag-major with kt innermost-but-one:
//   p1[ ((nt*16 + l)*8 + kt)*32 + kin ]  (nt<12, kt<8)  k = kt*32+kin, n = nt*16+l
//   p2[ ((nt*16 + l)*6 + kt)*32 + kin ]  (nt<8,  kt<6)
__global__ void pack_w(const float* __restrict__ W1, const float* __restrict__ W2,
                       unsigned short* __restrict__ p1, unsigned short* __restrict__ p2) {
    int i = blockIdx.x * 256 + threadIdx.x;
    if (i < 49152) {
        int kin = i & 31; int t = i >> 5;
        int kt = t & 7; t >>= 3;
        int l = t & 15; int nt = t >> 4;
        p1[i] = f2bf(W1[(kt * 32 + kin) * MID + nt * 16 + l]);
    }
    int j = i - 49152;
    if (j >= 0 && j < 24576) {
        int kin = j & 31; int t = j >> 5;
        int kt = t % 6; t /= 6;
        int l = t & 15; int nt = t >> 4;
        p2[j] = f2bf(W2[(kt * 32 + kin) * OUT_N + nt * 16 + l]);
    }
}

template<bool PREH>
__global__ __launch_bounds__(256, 5)
void edge_mlp(const float* __restrict__ h,
              const unsigned short* __restrict__ hb,
              const float* __restrict__ dR,
              const int* __restrict__ src_idx,
              const int* __restrict__ dst_idx,
              const float* __restrict__ W1,     // for dR row (k=256)
              const float* __restrict__ b1,
              const float* __restrict__ b2,
              const unsigned short* __restrict__ p1,
              const unsigned short* __restrict__ p2,
              float* __restrict__ out) {
    __shared__ __align__(16) unsigned short sH[M_TILE * H_STRIDE]; // 25600 B

    const int tid = threadIdx.x;
    const int e0 = blockIdx.x * M_TILE;
    const int lane = tid & 63;
    const int w = tid >> 6;          // wave 0..3 (n-split)
    const int l15 = lane & 15;
    const int q = lane >> 4;

    // this lane's a-frag row indices (row = m*16 + l15)
    int idxd[4], idxs[4];
#pragma unroll
    for (int m = 0; m < 4; ++m) {
        idxd[m] = dst_idx[e0 + m * 16 + l15];
        idxs[m] = src_idx[e0 + m * 16 + l15];
    }

    // ---- layer 1: acc1 = A @ W1 over K=256 (dR column is a rank-1 epilogue) ----
    const unsigned short* bb1[3];
#pragma unroll
    for (int ni = 0; ni < 3; ++ni) {
        int nt = w + ni * 4;
        bb1[ni] = p1 + nt * 4096 + l15 * 256 + q * 8;   // + kt*32 via imm offset
    }

    f32x4 acc1[4][3] = {};
#pragma unroll
    for (int kt = 0; kt < 8; ++kt) {
        const int part = kt >> 2, ktl = kt & 3;
        bf16x8 a[4];
#pragma unroll
        for (int m = 0; m < 4; ++m) {
            int idx = part ? idxs[m] : idxd[m];
            if (PREH) {
                a[m] = *(const bf16x8*)(hb + (size_t)idx * F_IN + ktl * 32 + q * 8);
            } else {
                const float* hp = h + (size_t)idx * F_IN + ktl * 32 + q * 8;
                float4 v0 = *(const float4*)hp;
                float4 v1 = *(const float4*)(hp + 4);
                bf16x8 t;
                t[0] = (short)f2bf(v0.x); t[1] = (short)f2bf(v0.y);
                t[2] = (short)f2bf(v0.z); t[3] = (short)f2bf(v0.w);
                t[4] = (short)f2bf(v1.x); t[5] = (short)f2bf(v1.y);
                t[6] = (short)f2bf(v1.z); t[7] = (short)f2bf(v1.w);
                a[m] = t;
            }
        }
#pragma unroll
        for (int ni = 0; ni < 3; ++ni) {
            bf16x8 bf = *(const bf16x8*)(bb1[ni] + kt * 32);
#pragma unroll
            for (int m = 0; m < 4; ++m)
                acc1[m][ni] = __builtin_amdgcn_mfma_f32_16x16x32_bf16(a[m], bf, acc1[m][ni], 0, 0, 0);
        }
    }

    // dR for this lane's C-layout rows (e = m*16 + q*4 + r)
    float dr[4][4];
#pragma unroll
    for (int m = 0; m < 4; ++m)
#pragma unroll
        for (int r = 0; r < 4; ++r)
            dr[m][r] = dR[e0 + m * 16 + q * 4 + r];

    // ---- epilogue 1: +b1 +dR*w_dr, relu, bf16 -> LDS hid ----
#pragma unroll
    for (int ni = 0; ni < 3; ++ni) {
        int n = (w + ni * 4) * 16 + l15;
        float bb = b1[n];
        float wd = W1[256 * MID + n];
#pragma unroll
        for (int m = 0; m < 4; ++m) {
#pragma unroll
            for (int r = 0; r < 4; ++r) {
                int e = m * 16 + q * 4 + r;
                float v = acc1[m][ni][r] + bb + dr[m][r] * wd;
                v = fmaxf(v, 0.0f);
                sH[e * H_STRIDE + n] = f2bf(v);
            }
        }
    }
    __syncthreads();   // the kernel's only barrier

    // ---- layer 2: out = tanh(hid @ W2 + b2); wave w owns n-tiles {w, w+4} ----
    const unsigned short* bb2[2];
#pragma unroll
    for (int ni = 0; ni < 2; ++ni) {
        int nt = w + ni * 4;
        bb2[ni] = p2 + nt * 3072 + l15 * 192 + q * 8;   // + kt*32 via imm offset
    }
    const unsigned short* arow[4];
#pragma unroll
    for (int m = 0; m < 4; ++m)
        arow[m] = sH + (m * 16 + l15) * H_STRIDE + q * 8;

    f32x4 acc2[4][2] = {};
#pragma unroll
    for (int kt = 0; kt < 6; ++kt) {
        bf16x8 a[4];
#pragma unroll
        for (int m = 0; m < 4; ++m)
            a[m] = *(const bf16x8*)(arow[m] + kt * 32);
#pragma unroll
        for (int ni = 0; ni < 2; ++ni) {
            bf16x8 bf = *(const bf16x8*)(bb2[ni] + kt * 32);
#pragma unroll
            for (int m = 0; m < 4; ++m)
                acc2[m][ni] = __builtin_amdgcn_mfma_f32_16x16x32_bf16(a[m], bf, acc2[m][ni], 0, 0, 0);
        }
    }

    // ---- epilogue 2: tanh = 1 - 2/(exp2(2*log2e*x)+1), nontemporal store ----
#pragma unroll
    for (int ni = 0; ni < 2; ++ni) {
        int n = (w + ni * 4) * 16 + l15;
        float bb = b2[n];
#pragma unroll
        for (int m = 0; m < 4; ++m) {
#pragma unroll
            for (int r = 0; r < 4; ++r) {
                int e = e0 + m * 16 + q * 4 + r;
                float x = acc2[m][ni][r] + bb;
                float t = __builtin_amdgcn_exp2f(x * 2.885390081777927f);
                float y = 1.0f - 2.0f * __builtin_amdgcn_rcpf(t + 1.0f);
                __builtin_nontemporal_store(y, out + (size_t)e * OUT_N + n);
            }
        }
    }
}

extern "C" void kernel_launch(void* const* d_in, const int* in_sizes, int n_in,
                              void* d_out, int out_size, void* d_ws, size_t ws_size,
                              hipStream_t stream) {
    const float* h   = (const float*)d_in[0];
    const float* dR  = (const float*)d_in[1];
    const int* src   = (const int*)d_in[2];
    const int* dst   = (const int*)d_in[3];
    const float* W1  = (const float*)d_in[4];
    const float* b1  = (const float*)d_in[5];
    const float* W2  = (const float*)d_in[6];
    const float* b2  = (const float*)d_in[7];
    float* out       = (float*)d_out;

    const int E = in_sizes[1];
    const int NNODES = in_sizes[0] / F_IN;

    unsigned short* p1 = (unsigned short*)d_ws;            // 49152 bf16
    unsigned short* p2 = p1 + 49152;                       // 24576 bf16
    unsigned short* hb = p2 + 24576;                       // NNODES*128 bf16
    const size_t need = (size_t)(49152 + 24576) * 2 + (size_t)NNODES * F_IN * 2;

    pack_w<<<288, 256, 0, stream>>>(W1, W2, p1, p2);

    if (ws_size >= need) {
        int n4 = NNODES * F_IN / 4;
        pack_h<<<(n4 + 255) / 256, 256, 0, stream>>>(h, hb, n4);
        edge_mlp<true><<<E / M_TILE, 256, 0, stream>>>(h, hb, dR, src, dst,
                                                       W1, b1, b2, p1, p2, out);
    } else {
        edge_mlp<false><<<E / M_TILE, 256, 0, stream>>>(h, hb, dR, src, dst,
                                                        W1, b1, b2, p1, p2, out);
    }
}